// Round 1
// baseline (39813.782 us; speedup 1.0000x reference)
//
#include <hip/hip_runtime.h>
#include <stdint.h>

typedef unsigned short u16;
typedef __bf16 bf16x8 __attribute__((ext_vector_type(8)));
typedef float f32x4 __attribute__((ext_vector_type(4)));

#define S_LEN 288
#define T_LEN 144
#define HID   512
#define BATCH 2048
#define NBLK  256
#define LDSN  5120               // u16 per LDS buffer: 128 rows * 40 (32 + 8 pad)
#define HBUF  ((size_t)BATCH * HID)

__device__ __forceinline__ u16 f2bf(float f){
  unsigned u = __builtin_bit_cast(unsigned, f);
  u = u + 0x7fffu + ((u >> 16) & 1u);
  return (u16)(u >> 16);
}
__device__ __forceinline__ float sigf(float x){ return 1.0f/(1.0f + __expf(-x)); }
__device__ __forceinline__ float tanh_f(float x){ return 1.0f - 2.0f/(1.0f + __expf(2.0f*x)); }

struct Params {
  const float* x;
  const u16 *We0, *We1i, *We1h, *Wd0, *Wd1i, *Wd1h;
  const float *be0, *be1, *bd0, *bd1, *wxe, *wxd, *fcW, *fcbp;
  u16 *h0buf, *h1buf;
  float* preds;
  unsigned* cnt;
  float* out;
};

// ---------------- prep kernels ----------------
// Reorder (4H,H) fp32 weights into gate-interleaved bf16:
// orig row = gate*512 + hu  ->  new row = (hu>>4)*64 + gate*16 + (hu&15)
__global__ void k_reorder_w(const float* __restrict__ src, u16* __restrict__ dst){
  int idx  = blockIdx.x * 256 + threadIdx.x;       // 2048*512 threads
  int k    = idx & (HID-1);
  int orig = idx >> 9;
  int gate = orig >> 9, hu = orig & (HID-1);
  int nr   = ((hu >> 4) << 6) + (gate << 4) + (hu & 15);
  dst[(size_t)nr * HID + k] = f2bf(src[idx]);
}

__global__ void k_prep_small(const float* __restrict__ bih, const float* __restrict__ bhh,
                             float* __restrict__ bdst,
                             const float* __restrict__ wcol, float* __restrict__ wdst){
  int orig = blockIdx.x * 256 + threadIdx.x;       // 0..2047
  int gate = orig >> 9, hu = orig & (HID-1);
  int nr   = ((hu >> 4) << 6) + (gate << 4) + (hu & 15);
  bdst[nr] = bih[orig] + bhh[orig];
  if (wcol) wdst[nr] = wcol[orig];
}

// ---------------- grid barrier (monotonic count) ----------------
__device__ __forceinline__ void gbar(unsigned* cnt, unsigned& epoch){
  __syncthreads();
  __threadfence();
  ++epoch;
  if (threadIdx.x == 0){
    atomicAdd(cnt, 1u);
    const unsigned tgt = epoch * NBLK;
    while (__hip_atomic_load(cnt, __ATOMIC_ACQUIRE, __HIP_MEMORY_SCOPE_AGENT) < tgt)
      __builtin_amdgcn_s_sleep(8);
  }
  __syncthreads();
  __threadfence();
}

// ---------------- one K=512 GEMM segment (128x128 tile) ----------------
// A: h rows [m-tile], stride 512. B (and B2 if DUAL): weight rows [n-tile], stride 512.
// acc/acc2: 4x4 f32x4 per wave (64x64 wave tile). LDS double buffered, chunk k=32.
template<bool DUAL>
__device__ __forceinline__ void gemm_seg(
    const u16* __restrict__ Asrc, const u16* __restrict__ Bsrc, const u16* __restrict__ B2src,
    u16* lA, u16* lB, u16* lB2,
    f32x4 (&acc)[4][4], f32x4 (&acc2)[4][4],
    int tid, int wm, int wn, int l15, int quad)
{
  const int flat0 = tid, flat1 = tid + 256;
  const int row0 = flat0 >> 2, q0 = flat0 & 3;
  const int row1 = flat1 >> 2, q1 = flat1 & 3;
  const size_t g0 = (size_t)row0*HID + q0*8;
  const size_t g1 = (size_t)row1*HID + q1*8;
  const int s0 = row0*40 + q0*8, s1 = row1*40 + q1*8;

  int4 ra0, ra1, rb0, rb1, rc0, rc1;
  ra0 = *(const int4*)(Asrc + g0); ra1 = *(const int4*)(Asrc + g1);
  rb0 = *(const int4*)(Bsrc + g0); rb1 = *(const int4*)(Bsrc + g1);
  if (DUAL){ rc0 = *(const int4*)(B2src + g0); rc1 = *(const int4*)(B2src + g1); }
  *(int4*)&lA[s0] = ra0; *(int4*)&lA[s1] = ra1;
  *(int4*)&lB[s0] = rb0; *(int4*)&lB[s1] = rb1;
  if (DUAL){ *(int4*)&lB2[s0] = rc0; *(int4*)&lB2[s1] = rc1; }
  __syncthreads();

  for (int c = 0; c < 16; ++c){
    const int cur = (c & 1) * LDSN, nxt = ((c+1) & 1) * LDSN;
    const bool more = (c < 15);
    if (more){
      const u16* a  = Asrc + (c+1)*32;
      const u16* b  = Bsrc + (c+1)*32;
      ra0 = *(const int4*)(a + g0); ra1 = *(const int4*)(a + g1);
      rb0 = *(const int4*)(b + g0); rb1 = *(const int4*)(b + g1);
      if (DUAL){
        const u16* b2 = B2src + (c+1)*32;
        rc0 = *(const int4*)(b2 + g0); rc1 = *(const int4*)(b2 + g1);
      }
    }
    bf16x8 af[4], bfr[4], b2f[4];
    #pragma unroll
    for (int mf = 0; mf < 4; ++mf)
      af[mf] = *(const bf16x8*)&lA[cur + (wm*64 + mf*16 + l15)*40 + quad*8];
    #pragma unroll
    for (int nf = 0; nf < 4; ++nf)
      bfr[nf] = *(const bf16x8*)&lB[cur + (wn*64 + nf*16 + l15)*40 + quad*8];
    if (DUAL){
      #pragma unroll
      for (int nf = 0; nf < 4; ++nf)
        b2f[nf] = *(const bf16x8*)&lB2[cur + (wn*64 + nf*16 + l15)*40 + quad*8];
    }
    #pragma unroll
    for (int mf = 0; mf < 4; ++mf){
      #pragma unroll
      for (int nf = 0; nf < 4; ++nf){
        acc[mf][nf] = __builtin_amdgcn_mfma_f32_16x16x32_bf16(af[mf], bfr[nf], acc[mf][nf], 0, 0, 0);
        if (DUAL)
          acc2[mf][nf] = __builtin_amdgcn_mfma_f32_16x16x32_bf16(af[mf], b2f[nf], acc2[mf][nf], 0, 0, 0);
      }
    }
    if (more){
      *(int4*)&lA[nxt + s0] = ra0; *(int4*)&lA[nxt + s1] = ra1;
      *(int4*)&lB[nxt + s0] = rb0; *(int4*)&lB[nxt + s1] = rb1;
      if (DUAL){ *(int4*)&lB2[nxt + s0] = rc0; *(int4*)&lB2[nxt + s1] = rc1; }
    }
    __syncthreads();
  }
}

// ---------------- LSTM cell epilogue (lane-local gates) ----------------
template<bool X0, bool PRED>
__device__ __forceinline__ void cell_epi(
    f32x4 (&acc)[4][4], float* cst, const float* bv, const float* wxv,
    const float* xin, u16* hdst,
    int m0, int wm, int quad, int l15, int hu,
    float fcWv, float* predrow)
{
  #pragma unroll
  for (int mf = 0; mf < 4; ++mf){
    #pragma unroll
    for (int r = 0; r < 4; ++r){
      const int b = m0 + wm*64 + mf*16 + quad*4 + r;
      float gi = acc[mf][0][r] + bv[0];
      float gf = acc[mf][1][r] + bv[1];
      float gg = acc[mf][2][r] + bv[2];
      float go = acc[mf][3][r] + bv[3];
      if (X0){
        const float xt = xin[mf*4 + r];
        gi += xt * wxv[0]; gf += xt * wxv[1]; gg += xt * wxv[2]; go += xt * wxv[3];
      }
      float c = sigf(gf) * cst[mf*4+r] + sigf(gi) * tanh_f(gg);
      cst[mf*4+r] = c;
      float h = sigf(go) * tanh_f(c);
      hdst[(size_t)b * HID + hu] = f2bf(h);
      if (PRED){
        float v = h * fcWv;
        v += __shfl_xor(v, 1); v += __shfl_xor(v, 2);
        v += __shfl_xor(v, 4); v += __shfl_xor(v, 8);
        if (l15 == 0) atomicAdd(&predrow[b], v);
      }
    }
  }
}

// ---------------- persistent main kernel ----------------
__global__ __launch_bounds__(256, 1) void lstm_main(Params P){
  const int tid   = threadIdx.x;
  const int bx    = blockIdx.x;
  const int xcd   = bx & 7, slot = bx >> 3;
  const int n_blk = xcd*2 + (slot & 1);   // same-n blocks share an XCD -> weights L2-resident
  const int m_blk = slot >> 1;
  const int m0 = m_blk * 128, n0 = n_blk * 128;
  const int wave = tid >> 6, lane = tid & 63;
  const int wm = wave >> 1, wn = wave & 1;
  const int l15 = lane & 15, quad = lane >> 4;
  const int hugrp = n_blk*2 + wn;
  const int hu = hugrp*16 + l15;

  __shared__ u16 sA[2*LDSN];
  __shared__ u16 sB[2*LDSN];
  __shared__ u16 sB2[2*LDSN];

  float c0s[16], c1s[16];
  #pragma unroll
  for (int i = 0; i < 16; ++i){ c0s[i] = 0.f; c1s[i] = 0.f; }

  float be0v[4], be1v[4], bd0v[4], bd1v[4], wxev[4], wxdv[4];
  #pragma unroll
  for (int g = 0; g < 4; ++g){
    const int col = hugrp*64 + g*16 + l15;
    be0v[g] = P.be0[col]; be1v[g] = P.be1[col];
    bd0v[g] = P.bd0[col]; bd1v[g] = P.bd1[col];
    wxev[g] = P.wxe[col]; wxdv[g] = P.wxd[col];
  }
  const float fcWv = P.fcW[hu];
  const float fcb  = P.fcbp[0];

  const size_t nb = (size_t)n0 * HID;
  const u16* We0b  = P.We0  + nb;
  const u16* We1ib = P.We1i + nb;
  const u16* We1hb = P.We1h + nb;
  const u16* Wd0b  = P.Wd0  + nb;
  const u16* Wd1ib = P.Wd1i + nb;
  const u16* Wd1hb = P.Wd1h + nb;
  const size_t mb = (size_t)m0 * HID;
  u16* h0b[2] = { P.h0buf, P.h0buf + HBUF };
  u16* h1b[2] = { P.h1buf, P.h1buf + HBUF };

  unsigned epoch = 0;

  // ===== encoder: phase p runs layer0(t=p) and layer1(t=p-1) =====
  for (int p = 0; p <= S_LEN; ++p){
    f32x4 acc0[4][4], acc1[4][4];
    #pragma unroll
    for (int i = 0; i < 4; ++i)
      #pragma unroll
      for (int j = 0; j < 4; ++j){ acc0[i][j] = f32x4{0.f,0.f,0.f,0.f}; acc1[i][j] = f32x4{0.f,0.f,0.f,0.f}; }

    // shared A = h0(p-1): layer0 recurrence + layer1 input GEMM (dual B)
    gemm_seg<true>(h0b[p & 1] + mb, We0b, We1ib, sA, sB, sB2, acc0, acc1, tid, wm, wn, l15, quad);
    // layer1 hidden GEMM: A = h1(p-2)
    gemm_seg<false>(h1b[(p+1) & 1] + mb, We1hb, We1hb, sA, sB, sB2, acc1, acc1, tid, wm, wn, l15, quad);

    if (p < S_LEN){
      float xin[16];
      #pragma unroll
      for (int mf = 0; mf < 4; ++mf)
        #pragma unroll
        for (int r = 0; r < 4; ++r){
          const int b = m0 + wm*64 + mf*16 + quad*4 + r;
          xin[mf*4+r] = P.x[(size_t)b*S_LEN + p];
        }
      cell_epi<true,false>(acc0, c0s, be0v, wxev, xin, h0b[(p+1) & 1],
                           m0, wm, quad, l15, hu, 0.f, nullptr);
    }
    if (p >= 1){
      cell_epi<false,false>(acc1, c1s, be1v, nullptr, nullptr, h1b[p & 1],
                            m0, wm, quad, l15, hu, 0.f, nullptr);
    }
    gbar(P.cnt, epoch);
  }

  // ===== decoder: 2 phases per step (pred feedback) =====
  for (int t = 0; t < T_LEN; ++t){
    // write out[:, t-1] from accumulated preds
    if (t > 0 && n_blk == 0 && tid < 128){
      P.out[(size_t)(m0 + tid)*T_LEN + (t-1)] =
          P.preds[((t+1) & 1)*BATCH + m0 + tid] + fcb;
    }
    { // phase A: dec layer0
      float xin[16];
      #pragma unroll
      for (int mf = 0; mf < 4; ++mf)
        #pragma unroll
        for (int r = 0; r < 4; ++r){
          const int b = m0 + wm*64 + mf*16 + quad*4 + r;
          xin[mf*4+r] = (t == 0) ? P.x[(size_t)b*S_LEN + (S_LEN-1)]
                                 : (P.preds[((t+1) & 1)*BATCH + b] + fcb);
        }
      f32x4 acc0[4][4];
      #pragma unroll
      for (int i = 0; i < 4; ++i)
        #pragma unroll
        for (int j = 0; j < 4; ++j) acc0[i][j] = f32x4{0.f,0.f,0.f,0.f};
      gemm_seg<false>(h0b[t & 1] + mb, Wd0b, Wd0b, sA, sB, sB2, acc0, acc0, tid, wm, wn, l15, quad);
      cell_epi<true,false>(acc0, c0s, bd0v, wxdv, xin, h0b[(t+1) & 1],
                           m0, wm, quad, l15, hu, 0.f, nullptr);
    }
    gbar(P.cnt, epoch);
    // phase B: dec layer1 + pred reduce
    if (n_blk == 0 && tid < 128)
      P.preds[((t+1) & 1)*BATCH + m0 + tid] = 0.f;   // recycle buffer for step t+1
    {
      f32x4 acc1[4][4];
      #pragma unroll
      for (int i = 0; i < 4; ++i)
        #pragma unroll
        for (int j = 0; j < 4; ++j) acc1[i][j] = f32x4{0.f,0.f,0.f,0.f};
      gemm_seg<false>(h0b[(t+1) & 1] + mb, Wd1ib, Wd1ib, sA, sB, sB2, acc1, acc1, tid, wm, wn, l15, quad);
      gemm_seg<false>(h1b[t & 1] + mb,     Wd1hb, Wd1hb, sA, sB, sB2, acc1, acc1, tid, wm, wn, l15, quad);
      cell_epi<false,true>(acc1, c1s, bd1v, nullptr, nullptr, h1b[(t+1) & 1],
                           m0, wm, quad, l15, hu, fcWv, P.preds + (t & 1)*BATCH);
    }
    gbar(P.cnt, epoch);
  }
  if (n_blk == 0 && tid < 128){
    P.out[(size_t)(m0 + tid)*T_LEN + (T_LEN-1)] =
        P.preds[((T_LEN-1) & 1)*BATCH + m0 + tid] + fcb;
  }
}

// ---------------- host launcher ----------------
extern "C" void kernel_launch(void* const* d_in, const int* in_sizes, int n_in,
                              void* d_out, int out_size, void* d_ws, size_t ws_size,
                              hipStream_t stream){
  const float* x     = (const float*)d_in[0];
  const float* eWih0 = (const float*)d_in[1];
  const float* eWhh0 = (const float*)d_in[2];
  const float* ebih0 = (const float*)d_in[3];
  const float* ebhh0 = (const float*)d_in[4];
  const float* eWih1 = (const float*)d_in[5];
  const float* eWhh1 = (const float*)d_in[6];
  const float* ebih1 = (const float*)d_in[7];
  const float* ebhh1 = (const float*)d_in[8];
  const float* dWih0 = (const float*)d_in[9];
  const float* dWhh0 = (const float*)d_in[10];
  const float* dbih0 = (const float*)d_in[11];
  const float* dbhh0 = (const float*)d_in[12];
  const float* dWih1 = (const float*)d_in[13];
  const float* dWhh1 = (const float*)d_in[14];
  const float* dbih1 = (const float*)d_in[15];
  const float* dbhh1 = (const float*)d_in[16];
  const float* fcW   = (const float*)d_in[17];
  const float* fcb   = (const float*)d_in[18];

  char* ws = (char*)d_ws;
  size_t off = 0;
  auto alloc = [&](size_t bytes)->char*{
    char* p = ws + off; off += (bytes + 255) & ~(size_t)255; return p;
  };
  u16* We0  = (u16*)alloc((size_t)2048*512*2);
  u16* We1i = (u16*)alloc((size_t)2048*512*2);
  u16* We1h = (u16*)alloc((size_t)2048*512*2);
  u16* Wd0  = (u16*)alloc((size_t)2048*512*2);
  u16* Wd1i = (u16*)alloc((size_t)2048*512*2);
  u16* Wd1h = (u16*)alloc((size_t)2048*512*2);
  char* zbase = ws + off;
  u16* h0buf = (u16*)alloc(2*HBUF*2);
  u16* h1buf = (u16*)alloc(2*HBUF*2);
  float* preds = (float*)alloc(2*BATCH*4);
  unsigned* cnt = (unsigned*)alloc(256);
  size_t zbytes = (size_t)((ws + off) - zbase);
  float* be0 = (float*)alloc(2048*4);
  float* be1 = (float*)alloc(2048*4);
  float* bd0 = (float*)alloc(2048*4);
  float* bd1 = (float*)alloc(2048*4);
  float* wxe = (float*)alloc(2048*4);
  float* wxd = (float*)alloc(2048*4);

  hipMemsetAsync(zbase, 0, zbytes, stream);
  dim3 gw((2048*512)/256);
  k_reorder_w<<<gw,256,0,stream>>>(eWhh0, We0);
  k_reorder_w<<<gw,256,0,stream>>>(eWih1, We1i);
  k_reorder_w<<<gw,256,0,stream>>>(eWhh1, We1h);
  k_reorder_w<<<gw,256,0,stream>>>(dWhh0, Wd0);
  k_reorder_w<<<gw,256,0,stream>>>(dWih1, Wd1i);
  k_reorder_w<<<gw,256,0,stream>>>(dWhh1, Wd1h);
  k_prep_small<<<8,256,0,stream>>>(ebih0, ebhh0, be0, eWih0, wxe);
  k_prep_small<<<8,256,0,stream>>>(ebih1, ebhh1, be1, (const float*)nullptr, (float*)nullptr);
  k_prep_small<<<8,256,0,stream>>>(dbih0, dbhh0, bd0, dWih0, wxd);
  k_prep_small<<<8,256,0,stream>>>(dbih1, dbhh1, bd1, (const float*)nullptr, (float*)nullptr);

  Params P{ x, We0, We1i, We1h, Wd0, Wd1i, Wd1h,
            be0, be1, bd0, bd1, wxe, wxd, fcW, fcb,
            h0buf, h1buf, preds, cnt, (float*)d_out };
  void* args[] = { &P };
  hipError_t e = hipLaunchCooperativeKernel((const void*)lstm_main,
                                            dim3(NBLK), dim3(256), args, 0, stream);
  if (e != hipSuccess){
    // co-residency holds anyway at 1 block/CU on an idle device
    lstm_main<<<dim3(NBLK), dim3(256), 0, stream>>>(P);
  }
}

// Round 2
// 29378.348 us; speedup vs baseline: 1.3552x; 1.3552x over previous
//
#include <hip/hip_runtime.h>
#include <stdint.h>

typedef unsigned short u16;
typedef unsigned long long u64;
typedef __bf16 bf16x8 __attribute__((ext_vector_type(8)));
typedef float f32x4 __attribute__((ext_vector_type(4)));

#define S_LEN 288
#define T_LEN 144
#define HID   512
#define BATCH 2048
#define NBLK  512
#define HBUF  ((size_t)BATCH * HID)
#define ABUF  2048   // u16 per A LDS buffer (64 rows x 32)
#define BBUF  4096   // u16 per B LDS buffer (128 rows x 32)
// XOR swizzle: row stride 32 u16 (64B), 16B slot q ^ ((row>>1)&3) -> conflict-free
#define SW(r,q) (((r)<<5) + ((((q) ^ (((r)>>1)&3)))<<3))

__device__ __forceinline__ u16 f2bf(float f){
  unsigned u = __builtin_bit_cast(unsigned, f);
  u = u + 0x7fffu + ((u >> 16) & 1u);
  return (u16)(u >> 16);
}
__device__ __forceinline__ float sigf(float x){ return 1.0f/(1.0f + __expf(-x)); }
__device__ __forceinline__ float tanh_f(float x){ return 1.0f - 2.0f/(1.0f + __expf(2.0f*x)); }

// agent-scope (sc1) accesses: bypass per-XCD L2, coherent at memory-side L3.
__device__ __forceinline__ u64 aload64(const void* p){
  return __hip_atomic_load((const u64*)p, __ATOMIC_RELAXED, __HIP_MEMORY_SCOPE_AGENT);
}
__device__ __forceinline__ float aloadf(const float* p){
  return __hip_atomic_load(p, __ATOMIC_RELAXED, __HIP_MEMORY_SCOPE_AGENT);
}
__device__ __forceinline__ void astore64(void* p, u64 v){
  __hip_atomic_store((u64*)p, v, __ATOMIC_RELAXED, __HIP_MEMORY_SCOPE_AGENT);
}
__device__ __forceinline__ void astoref(float* p, float v){
  __hip_atomic_store(p, v, __ATOMIC_RELAXED, __HIP_MEMORY_SCOPE_AGENT);
}

struct Params {
  const float* x;
  const u16 *We0, *We1i, *We1h, *Wd0, *Wd1i, *Wd1h;
  const float *be0, *be1, *bd0, *bd1, *wxe, *wxd, *fcW, *fcbp;
  u16 *h0buf, *h1buf;
  float* preds;
  unsigned* cnt;
  float* out;
};

// ---------------- prep kernels ----------------
__global__ void k_reorder_w(const float* __restrict__ src, u16* __restrict__ dst){
  int idx  = blockIdx.x * 256 + threadIdx.x;       // 2048*512 threads
  int k    = idx & (HID-1);
  int orig = idx >> 9;
  int gate = orig >> 9, hu = orig & (HID-1);
  int nr   = ((hu >> 4) << 6) + (gate << 4) + (hu & 15);
  dst[(size_t)nr * HID + k] = f2bf(src[idx]);
}

__global__ void k_prep_small(const float* __restrict__ bih, const float* __restrict__ bhh,
                             float* __restrict__ bdst,
                             const float* __restrict__ wcol, float* __restrict__ wdst){
  int orig = blockIdx.x * 256 + threadIdx.x;       // 0..2047
  int gate = orig >> 9, hu = orig & (HID-1);
  int nr   = ((hu >> 4) << 6) + (gate << 4) + (hu & 15);
  bdst[nr] = bih[orig] + bhh[orig];
  if (wcol) wdst[nr] = wcol[orig];
}

// ---------------- grid barrier: NO cache invalidation ----------------
// RELEASE fetch_add -> s_waitcnt + buffer_wbl2 (writeback only, L2 stays valid).
// RELAXED poll (sc1 load, bypasses L2). Data visibility relies on all
// cross-block data using agent-scope (sc1) accesses.
__device__ __forceinline__ void gbar(unsigned* cnt, unsigned& epoch){
  __syncthreads();
  ++epoch;
  if (threadIdx.x == 0){
    __hip_atomic_fetch_add(cnt, 1u, __ATOMIC_RELEASE, __HIP_MEMORY_SCOPE_AGENT);
    const unsigned tgt = epoch * NBLK;
    while (__hip_atomic_load(cnt, __ATOMIC_RELAXED, __HIP_MEMORY_SCOPE_AGENT) < tgt)
      __builtin_amdgcn_s_sleep(2);
  }
  __syncthreads();
}

// ---------------- one K=512 GEMM segment (64m x 128n tile) ----------------
template<bool DUAL>
__device__ __forceinline__ void gemm_seg(
    const u16* __restrict__ Asrc, const u16* __restrict__ Bsrc, const u16* __restrict__ B2src,
    u16* lA, u16* lB, u16* lB2,
    f32x4 (&acc)[2][4], f32x4 (&acc2)[2][4],
    int tid, int wm, int wn, int l15, int quad)
{
  const int r0 = tid >> 2, q0 = tid & 3;           // A rows 0..63, B rows r0 & r0+64
  const size_t ga  = (size_t)r0*HID + q0*8;
  const size_t gb1 = (size_t)(r0+64)*HID + q0*8;
  const int sa  = SW(r0, q0);
  const int sb1 = SW(r0+64, q0);

  u64 alo, ahi; int4 rb0, rb1, rc0, rc1;
  alo = aload64(Asrc + ga);
  ahi = aload64(Asrc + ga + 4);
  rb0 = *(const int4*)(Bsrc + ga); rb1 = *(const int4*)(Bsrc + gb1);
  if (DUAL){ rc0 = *(const int4*)(B2src + ga); rc1 = *(const int4*)(B2src + gb1); }
  ((u64*)(lA + sa))[0] = alo; ((u64*)(lA + sa))[1] = ahi;
  *(int4*)(lB + sa) = rb0; *(int4*)(lB + sb1) = rb1;
  if (DUAL){ *(int4*)(lB2 + sa) = rc0; *(int4*)(lB2 + sb1) = rc1; }
  __syncthreads();

  for (int c = 0; c < 16; ++c){
    const int pa = (c & 1) * ABUF, pb = (c & 1) * BBUF;
    const int na = ((c+1) & 1) * ABUF, nb = ((c+1) & 1) * BBUF;
    if (c < 15){
      const int ko = (c+1)*32;
      alo = aload64(Asrc + ko + ga);
      ahi = aload64(Asrc + ko + ga + 4);
      rb0 = *(const int4*)(Bsrc + ko + ga); rb1 = *(const int4*)(Bsrc + ko + gb1);
      if (DUAL){ rc0 = *(const int4*)(B2src + ko + ga); rc1 = *(const int4*)(B2src + ko + gb1); }
    }
    bf16x8 af[2], bfr[4], b2f[4];
    #pragma unroll
    for (int mf = 0; mf < 2; ++mf)
      af[mf] = *(const bf16x8*)&lA[pa + SW(wm*32 + mf*16 + l15, quad)];
    #pragma unroll
    for (int nf = 0; nf < 4; ++nf)
      bfr[nf] = *(const bf16x8*)&lB[pb + SW(wn*64 + nf*16 + l15, quad)];
    if (DUAL){
      #pragma unroll
      for (int nf = 0; nf < 4; ++nf)
        b2f[nf] = *(const bf16x8*)&lB2[pb + SW(wn*64 + nf*16 + l15, quad)];
    }
    #pragma unroll
    for (int mf = 0; mf < 2; ++mf){
      #pragma unroll
      for (int nf = 0; nf < 4; ++nf){
        acc[mf][nf] = __builtin_amdgcn_mfma_f32_16x16x32_bf16(af[mf], bfr[nf], acc[mf][nf], 0, 0, 0);
        if (DUAL)
          acc2[mf][nf] = __builtin_amdgcn_mfma_f32_16x16x32_bf16(af[mf], b2f[nf], acc2[mf][nf], 0, 0, 0);
      }
    }
    if (c < 15){
      ((u64*)(lA + na + sa))[0] = alo; ((u64*)(lA + na + sa))[1] = ahi;
      *(int4*)(lB + nb + sa) = rb0; *(int4*)(lB + nb + sb1) = rb1;
      if (DUAL){ *(int4*)(lB2 + nb + sa) = rc0; *(int4*)(lB2 + nb + sb1) = rc1; }
    }
    __syncthreads();
  }
}

// ---------------- LSTM cell epilogue: gates -> c,h; h into LDS scratch ----------------
// scratch layout: [64 rows][40 u16] (32 cols + pad, 16B-aligned rows)
template<bool X0, bool PRED>
__device__ __forceinline__ void cell_epi(
    f32x4 (&acc)[2][4], float* cst, const float* bv, const float* wxv,
    const float* xin, u16* scr,
    int wm, int wn, int quad, int l15, int m0,
    float fcWv, float* predrow)
{
  #pragma unroll
  for (int mf = 0; mf < 2; ++mf){
    #pragma unroll
    for (int r = 0; r < 4; ++r){
      float gi = acc[mf][0][r] + bv[0];
      float gf = acc[mf][1][r] + bv[1];
      float gg = acc[mf][2][r] + bv[2];
      float go = acc[mf][3][r] + bv[3];
      if (X0){
        const float xt = xin[mf*4 + r];
        gi += xt * wxv[0]; gf += xt * wxv[1]; gg += xt * wxv[2]; go += xt * wxv[3];
      }
      float c = sigf(gf) * cst[mf*4+r] + sigf(gi) * tanh_f(gg);
      cst[mf*4+r] = c;
      float h = sigf(go) * tanh_f(c);
      const int lb = wm*32 + mf*16 + quad*4 + r;
      scr[lb*40 + wn*16 + l15] = f2bf(h);
      if (PRED){
        float v = h * fcWv;
        v += __shfl_xor(v, 1); v += __shfl_xor(v, 2);
        v += __shfl_xor(v, 4); v += __shfl_xor(v, 8);
        if (l15 == 0) atomicAdd(&predrow[m0 + lb], v);
      }
    }
  }
}

// drain scratch -> global h (agent-scope, vectorized 16B/thread)
__device__ __forceinline__ void drain_h(const u16* scr, u16* hdst, int m0, int col0, int tid){
  __syncthreads();
  const int row = tid >> 2, q = tid & 3;
  const u64* s = (const u64*)(scr + row*40 + q*8);
  const u64 lo = s[0], hi = s[1];
  u64* d = (u64*)(hdst + (size_t)(m0+row)*HID + col0 + q*8);
  astore64(d, lo);
  astore64(d+1, hi);
  __syncthreads();
}

// ---------------- persistent main kernel ----------------
__global__ __launch_bounds__(256, 2) void lstm_main(Params P){
  const int tid   = threadIdx.x;
  const int bx    = blockIdx.x;
  const int xcd   = bx & 7, slot = bx >> 3;       // slot 0..63
  const int n_blk = xcd*2 + (slot & 1);           // 0..15, same-n per XCD -> weights L2-resident
  const int m_blk = slot >> 1;                    // 0..31
  const int m0 = m_blk * 64, n0 = n_blk * 128;
  const int wave = tid >> 6, lane = tid & 63;
  const int wm = wave >> 1, wn = wave & 1;
  const int l15 = lane & 15, quad = lane >> 4;
  const int hugrp = n_blk*2 + wn;
  const int hu = hugrp*16 + l15;
  const int col0 = n_blk*32;

  __shared__ u16 sA[2*ABUF];
  __shared__ u16 sB[2*BBUF];
  __shared__ u16 sB2[2*BBUF];
  u16* scr = sA;   // 2560 u16 scratch overlay (safe between segments)

  float c0s[8], c1s[8];
  #pragma unroll
  for (int i = 0; i < 8; ++i){ c0s[i] = 0.f; c1s[i] = 0.f; }

  float be0v[4], be1v[4], bd0v[4], bd1v[4], wxev[4], wxdv[4];
  #pragma unroll
  for (int g = 0; g < 4; ++g){
    const int col = hugrp*64 + g*16 + l15;
    be0v[g] = P.be0[col]; be1v[g] = P.be1[col];
    bd0v[g] = P.bd0[col]; bd1v[g] = P.bd1[col];
    wxev[g] = P.wxe[col]; wxdv[g] = P.wxd[col];
  }
  const float fcWv = P.fcW[hu];
  const float fcb  = P.fcbp[0];

  const size_t nb = (size_t)n0 * HID;
  const u16* We0b  = P.We0  + nb;
  const u16* We1ib = P.We1i + nb;
  const u16* We1hb = P.We1h + nb;
  const u16* Wd0b  = P.Wd0  + nb;
  const u16* Wd1ib = P.Wd1i + nb;
  const u16* Wd1hb = P.Wd1h + nb;
  const size_t mb = (size_t)m0 * HID;
  u16* h0b[2] = { P.h0buf, P.h0buf + HBUF };
  u16* h1b[2] = { P.h1buf, P.h1buf + HBUF };

  unsigned epoch = 0;

  // ===== encoder: phase p runs layer0(t=p) and layer1(t=p-1) =====
  for (int p = 0; p <= S_LEN; ++p){
    f32x4 acc0[2][4], acc1[2][4];
    #pragma unroll
    for (int i = 0; i < 2; ++i)
      #pragma unroll
      for (int j = 0; j < 4; ++j){ acc0[i][j] = f32x4{0.f,0.f,0.f,0.f}; acc1[i][j] = f32x4{0.f,0.f,0.f,0.f}; }

    // shared A = h0(p-1): layer0 recurrence + layer1 input GEMM (dual B)
    gemm_seg<true>(h0b[p & 1] + mb, We0b, We1ib, sA, sB, sB2, acc0, acc1, tid, wm, wn, l15, quad);
    // layer1 hidden GEMM: A = h1(p-2)
    gemm_seg<false>(h1b[(p+1) & 1] + mb, We1hb, We1hb, sA, sB, sB2, acc1, acc1, tid, wm, wn, l15, quad);

    if (p < S_LEN){
      float xin[8];
      #pragma unroll
      for (int mf = 0; mf < 2; ++mf)
        #pragma unroll
        for (int r = 0; r < 4; ++r){
          const int b = m0 + wm*32 + mf*16 + quad*4 + r;
          xin[mf*4+r] = P.x[(size_t)b*S_LEN + p];
        }
      cell_epi<true,false>(acc0, c0s, be0v, wxev, xin, scr, wm, wn, quad, l15, m0, 0.f, nullptr);
      drain_h(scr, h0b[(p+1) & 1], m0, col0, tid);
    }
    if (p >= 1){
      cell_epi<false,false>(acc1, c1s, be1v, nullptr, nullptr, scr, wm, wn, quad, l15, m0, 0.f, nullptr);
      drain_h(scr, h1b[p & 1], m0, col0, tid);
    }
    gbar(P.cnt, epoch);
  }

  // ===== decoder: 2 phases per step (pred feedback) =====
  for (int t = 0; t < T_LEN; ++t){
    if (t > 0 && n_blk == 0 && tid < 64){
      const float pv = aloadf(&P.preds[((t+1) & 1)*BATCH + m0 + tid]);
      P.out[(size_t)(m0 + tid)*T_LEN + (t-1)] = pv + fcb;
    }
    { // phase A: dec layer0
      float xin[8];
      #pragma unroll
      for (int mf = 0; mf < 2; ++mf)
        #pragma unroll
        for (int r = 0; r < 4; ++r){
          const int b = m0 + wm*32 + mf*16 + quad*4 + r;
          xin[mf*4+r] = (t == 0) ? P.x[(size_t)b*S_LEN + (S_LEN-1)]
                                 : (aloadf(&P.preds[((t+1) & 1)*BATCH + b]) + fcb);
        }
      f32x4 acc0[2][4];
      #pragma unroll
      for (int i = 0; i < 2; ++i)
        #pragma unroll
        for (int j = 0; j < 4; ++j) acc0[i][j] = f32x4{0.f,0.f,0.f,0.f};
      gemm_seg<false>(h0b[t & 1] + mb, Wd0b, Wd0b, sA, sB, sB2, acc0, acc0, tid, wm, wn, l15, quad);
      cell_epi<true,false>(acc0, c0s, bd0v, wxdv, xin, scr, wm, wn, quad, l15, m0, 0.f, nullptr);
      drain_h(scr, h0b[(t+1) & 1], m0, col0, tid);
    }
    gbar(P.cnt, epoch);
    // phase B: dec layer1 + pred reduce
    if (n_blk == 0 && tid < 64)
      astoref(&P.preds[((t+1) & 1)*BATCH + m0 + tid], 0.f);   // recycle for step t+1
    {
      f32x4 acc1[2][4];
      #pragma unroll
      for (int i = 0; i < 2; ++i)
        #pragma unroll
        for (int j = 0; j < 4; ++j) acc1[i][j] = f32x4{0.f,0.f,0.f,0.f};
      gemm_seg<false>(h0b[(t+1) & 1] + mb, Wd1ib, Wd1ib, sA, sB, sB2, acc1, acc1, tid, wm, wn, l15, quad);
      gemm_seg<false>(h1b[t & 1] + mb,     Wd1hb, Wd1hb, sA, sB, sB2, acc1, acc1, tid, wm, wn, l15, quad);
      cell_epi<false,true>(acc1, c1s, bd1v, nullptr, nullptr, scr, wm, wn, quad, l15, m0,
                           fcWv, P.preds + (t & 1)*BATCH);
      drain_h(scr, h1b[(t+1) & 1], m0, col0, tid);
    }
    gbar(P.cnt, epoch);
  }
  if (n_blk == 0 && tid < 64){
    const float pv = aloadf(&P.preds[((T_LEN-1) & 1)*BATCH + m0 + tid]);
    P.out[(size_t)(m0 + tid)*T_LEN + (T_LEN-1)] = pv + fcb;
  }
}

// ---------------- host launcher ----------------
extern "C" void kernel_launch(void* const* d_in, const int* in_sizes, int n_in,
                              void* d_out, int out_size, void* d_ws, size_t ws_size,
                              hipStream_t stream){
  const float* x     = (const float*)d_in[0];
  const float* eWih0 = (const float*)d_in[1];
  const float* eWhh0 = (const float*)d_in[2];
  const float* ebih0 = (const float*)d_in[3];
  const float* ebhh0 = (const float*)d_in[4];
  const float* eWih1 = (const float*)d_in[5];
  const float* eWhh1 = (const float*)d_in[6];
  const float* ebih1 = (const float*)d_in[7];
  const float* ebhh1 = (const float*)d_in[8];
  const float* dWih0 = (const float*)d_in[9];
  const float* dWhh0 = (const float*)d_in[10];
  const float* dbih0 = (const float*)d_in[11];
  const float* dbhh0 = (const float*)d_in[12];
  const float* dWih1 = (const float*)d_in[13];
  const float* dWhh1 = (const float*)d_in[14];
  const float* dbih1 = (const float*)d_in[15];
  const float* dbhh1 = (const float*)d_in[16];
  const float* fcW   = (const float*)d_in[17];
  const float* fcb   = (const float*)d_in[18];

  char* ws = (char*)d_ws;
  size_t off = 0;
  auto alloc = [&](size_t bytes)->char*{
    char* p = ws + off; off += (bytes + 255) & ~(size_t)255; return p;
  };
  u16* We0  = (u16*)alloc((size_t)2048*512*2);
  u16* We1i = (u16*)alloc((size_t)2048*512*2);
  u16* We1h = (u16*)alloc((size_t)2048*512*2);
  u16* Wd0  = (u16*)alloc((size_t)2048*512*2);
  u16* Wd1i = (u16*)alloc((size_t)2048*512*2);
  u16* Wd1h = (u16*)alloc((size_t)2048*512*2);
  char* zbase = ws + off;
  u16* h0buf = (u16*)alloc(2*HBUF*2);
  u16* h1buf = (u16*)alloc(2*HBUF*2);
  float* preds = (float*)alloc(2*BATCH*4);
  unsigned* cnt = (unsigned*)alloc(256);
  size_t zbytes = (size_t)((ws + off) - zbase);
  float* be0 = (float*)alloc(2048*4);
  float* be1 = (float*)alloc(2048*4);
  float* bd0 = (float*)alloc(2048*4);
  float* bd1 = (float*)alloc(2048*4);
  float* wxe = (float*)alloc(2048*4);
  float* wxd = (float*)alloc(2048*4);

  hipMemsetAsync(zbase, 0, zbytes, stream);
  dim3 gw((2048*512)/256);
  k_reorder_w<<<gw,256,0,stream>>>(eWhh0, We0);
  k_reorder_w<<<gw,256,0,stream>>>(eWih1, We1i);
  k_reorder_w<<<gw,256,0,stream>>>(eWhh1, We1h);
  k_reorder_w<<<gw,256,0,stream>>>(dWhh0, Wd0);
  k_reorder_w<<<gw,256,0,stream>>>(dWih1, Wd1i);
  k_reorder_w<<<gw,256,0,stream>>>(dWhh1, Wd1h);
  k_prep_small<<<8,256,0,stream>>>(ebih0, ebhh0, be0, eWih0, wxe);
  k_prep_small<<<8,256,0,stream>>>(ebih1, ebhh1, be1, (const float*)nullptr, (float*)nullptr);
  k_prep_small<<<8,256,0,stream>>>(dbih0, dbhh0, bd0, dWih0, wxd);
  k_prep_small<<<8,256,0,stream>>>(dbih1, dbhh1, bd1, (const float*)nullptr, (float*)nullptr);

  Params P{ x, We0, We1i, We1h, Wd0, Wd1i, Wd1h,
            be0, be1, bd0, bd1, wxe, wxd, fcW, fcb,
            h0buf, h1buf, preds, cnt, (float*)d_out };
  void* args[] = { &P };
  hipError_t e = hipLaunchCooperativeKernel((const void*)lstm_main,
                                            dim3(NBLK), dim3(256), args, 0, stream);
  if (e != hipSuccess){
    // 512 blocks at 2/CU fit the whole device; plain launch co-schedules on idle HW
    lstm_main<<<dim3(NBLK), dim3(256), 0, stream>>>(P);
  }
}